// Round 22
// baseline (163.089 us; speedup 1.0000x reference)
//
#include <hip/hip_runtime.h>

#define BATCH 32
#define NCAPS 32
#define NR    4608
#define NI    8
#define NO    16
#define CSTR  200    // R12 fallback LDS stride (proven)
#define CSW   129    // MFMA W-tile stride: 129 = 1 mod 32 -> conflict-free reads
#define CSX   9      // x-tile stride: 9 coprime 32 -> conflict-free b-indexed reads
#define UTS   520    // Ut row stride (ushorts)
#define MAXRB 36
#define NCH   256
#define L2E   1.44269504088896341f

typedef float f2 __attribute__((ext_vector_type(2)));
typedef _Float16 half4v __attribute__((ext_vector_type(4)));
typedef _Float16 half8v __attribute__((ext_vector_type(8)));
typedef float f32x16 __attribute__((ext_vector_type(16)));

// ================= PASS 1 (MFMA + LDS-transposed coalesced U stores) ==============
// R21-proven: 47us, 4.43 TB/s, absmax 0.0039.
template<int RB>
__global__ __launch_bounds__(1024, 1) void caps_route_store(
    const float* __restrict__ x,    // [B][R][I]
    const float* __restrict__ W,    // [C][R][I][O]
    float* __restrict__ P,          // [NCH][B][O][C]
    unsigned short* __restrict__ Uh)// [R][B][O][C] f16
{
    constexpr int NP = RB / 2;
    __shared__ __align__(16) float Ws2[2][2][NCAPS * CSW];          // 66.0 KB
    __shared__ __align__(16) float xQ[RB][BATCH * CSX];             // 20.7 KB
    __shared__ __align__(16) unsigned short Ut[2][BATCH][UTS];      // 66.6 KB

    const int t    = threadIdx.x;
    const int lane = t & 63;
    const int wv   = t >> 6;        // wave id = o (16 waves)
    const int cc   = lane & 31;
    const int h    = lane >> 5;
    const int r0   = blockIdx.x * RB;

    for (int s = t; s < RB * BATCH; s += 1024) {
        const int rr = s >> 5, b = s & 31;
        const float* xp = &x[((size_t)b * NR + r0 + rr) * NI];
        const float4 v0 = *(const float4*)xp;
        const float4 v1 = *(const float4*)(xp + 4);
        float* d = &xQ[rr][b * CSX];
        d[0] = v0.x; d[1] = v0.y; d[2] = v0.z; d[3] = v0.w;
        d[4] = v1.x; d[5] = v1.y; d[6] = v1.z; d[7] = v1.w;
    }

    const int c_st = t >> 5;
    const int part = t & 31;
    const int dstw = c_st * CSW + part * 4;
    const float* wsrc = W + ((size_t)c_st * NR + r0) * (NI * NO) + part * 4;

    {
        const float4 s0 = *(const float4*)wsrc;
        const float4 s1 = *(const float4*)(wsrc + NI * NO);
        float* d0 = &Ws2[0][0][dstw];
        d0[0] = s0.x; d0[1] = s0.y; d0[2] = s0.z; d0[3] = s0.w;
        float* d1 = &Ws2[0][1][dstw];
        d1[0] = s1.x; d1[1] = s1.y; d1[2] = s1.z; d1[3] = s1.w;
    }
    float4 pfa = {}, pfb = {};
    if (NP > 1) {
        pfa = *(const float4*)(wsrc + 2 * NI * NO);
        pfb = *(const float4*)(wsrc + 3 * NI * NO);
    }
    __syncthreads();

    f32x16 acc = (f32x16)0.f;
    const int xoff = cc * CSX + 4 * h;
    const int woff = cc * CSW + 64 * h + wv;
    const size_t S = (size_t)BATCH * NO * NCAPS;   // ushorts per r-slab

#pragma unroll 1
    for (int rp = 0; rp < NP; ++rp) {
        const int cur = rp & 1;
        if (rp + 1 < NP) {
            float* d0 = &Ws2[cur ^ 1][0][dstw];
            d0[0] = pfa.x; d0[1] = pfa.y; d0[2] = pfa.z; d0[3] = pfa.w;
            float* d1 = &Ws2[cur ^ 1][1][dstw];
            d1[0] = pfb.x; d1[1] = pfb.y; d1[2] = pfb.z; d1[3] = pfb.w;
            if (rp + 2 < NP) {
                pfa = *(const float4*)(wsrc + (size_t)(2 * rp + 4) * (NI * NO));
                pfb = *(const float4*)(wsrc + (size_t)(2 * rp + 5) * (NI * NO));
            }
        }

#pragma unroll
        for (int sub = 0; sub < 2; ++sub) {
            const float* xr = &xQ[2 * rp + sub][xoff];
            const float* wr = &Ws2[cur][sub][woff];
            half4v af, bf;
            af[0] = (_Float16)xr[0]; af[1] = (_Float16)xr[1];
            af[2] = (_Float16)xr[2]; af[3] = (_Float16)xr[3];
            bf[0] = (_Float16)wr[0];  bf[1] = (_Float16)wr[16];
            bf[2] = (_Float16)wr[32]; bf[3] = (_Float16)wr[48];
            const f32x16 u =
                __builtin_amdgcn_mfma_f32_32x32x8f16(af, bf, (f32x16)0.f, 0, 0, 0);
            acc += u;
#pragma unroll
            for (int k = 0; k < 16; ++k) {
                const int b = (k & 3) + 8 * (k >> 2) + 4 * h;
                const _Float16 hv = (_Float16)u[k];
                Ut[sub][b][wv * NCAPS + cc] = __builtin_bit_cast(unsigned short, hv);
            }
        }
        __syncthreads();   // Ut complete (and next Ws2 staged)

#pragma unroll
        for (int sub = 0; sub < 2; ++sub) {
            const size_t rbase = (size_t)(r0 + 2 * rp + sub) * S;
#pragma unroll
            for (int q = 0; q < 2; ++q) {
                const int s = t + 1024 * q;
                const int b = s >> 6;
                const int j = s & 63;
                const uint4 v = *(const uint4*)&Ut[sub][b][j * 8];
                *(uint4*)(Uh + rbase + (size_t)s * 8) = v;
            }
        }
        __syncthreads();   // Ut reads done before next writes
    }

    float* pb = P + ((size_t)blockIdx.x * BATCH * NO + wv) * NCAPS + cc;
#pragma unroll
    for (int k = 0; k < 16; ++k) {
        const int b = (k & 3) + 8 * (k >> 2) + 4 * h;
        pb[(size_t)b * (NO * NCAPS)] = acc[k] * 0.03125f;
    }
}

// ================= PASS 2/3: streaming softmax from cached U (at read ceiling) ====
template<int RB>
__global__ __launch_bounds__(1024, 2) void caps_route_cached(
    const unsigned short* __restrict__ Uh,  // [R][B][O][C] f16
    const float* __restrict__ A,            // [B][C][O]
    float* __restrict__ P)                  // [NCH][B][O][C]
{
    const int t     = threadIdx.x;
    const int ch2   = t & 3;
    const int o     = (t >> 2) & 15;
    const int brel  = t >> 6;
    const int chunk = blockIdx.x >> 1;
    const int b     = 16 * (blockIdx.x & 1) + brel;
    const int r0    = chunk * RB;

    float a2[8];
#pragma unroll
    for (int cc = 0; cc < 8; ++cc)
        a2[cc] = A[(b * NCAPS + 8 * ch2 + cc) * NO + o] * L2E;
    float acc[8];
#pragma unroll
    for (int cc = 0; cc < 8; ++cc) acc[cc] = 0.f;

    const size_t S = (size_t)BATCH * NO * NCAPS;
    const unsigned short* up =
        Uh + (((size_t)r0 * BATCH + b) * NO + o) * NCAPS + 8 * ch2;

    uint4 q = *(const uint4*)up;
#pragma unroll 1
    for (int rr = 0; rr < RB; ++rr) {
        uint4 n = {};
        if (rr + 1 < RB) n = *(const uint4*)(up + S);
        up += S;

        const half8v h = __builtin_bit_cast(half8v, q);
        float Z = 0.f;
        float tt[8];
#pragma unroll
        for (int cc = 0; cc < 8; ++cc) {
            const float uu = (float)h[cc];
            const float ee = exp2f(uu * a2[cc]);
            Z += ee;
            tt[cc] = ee * uu;
        }
        Z += __shfl_xor(Z, 1);
        Z += __shfl_xor(Z, 2);
        const float rz = __builtin_amdgcn_rcpf(Z);
#pragma unroll
        for (int cc = 0; cc < 8; ++cc)
            acc[cc] = fmaf(tt[cc], rz, acc[cc]);

        q = n;
    }

    float* pout = P + (((size_t)chunk * BATCH + b) * NO + o) * NCAPS + 8 * ch2;
    float4 v0, v1;
    v0.x = acc[0]; v0.y = acc[1]; v0.z = acc[2]; v0.w = acc[3];
    v1.x = acc[4]; v1.y = acc[5]; v1.z = acc[6]; v1.w = acc[7];
    *(float4*)pout = v0;
    *(float4*)(pout + 4) = v1;
}

// Fused reduce+squash: block per b streams P[0..255][b][*] (512 KB, coalesced
// 2KB rows, fixed-order deterministic sums), combines in LDS, squashes, updates
// A (FIRSTCALL: A = V, removing the separate zero kernel), emits V on last iter.
template<bool FIRSTCALL>
__global__ __launch_bounds__(1024) void caps_squash_all(
    const float* __restrict__ P,    // [NCH][B][O][C]
    float* __restrict__ A,
    float* __restrict__ out)
{
    __shared__ float sm[1024];
    __shared__ float sc[NCAPS];
    const int b   = blockIdx.x;
    const int t   = threadIdx.x;
    const int pos = t & 511;        // o*32 + c
    const int j   = t >> 9;         // chunk parity
    const float* pb = P + (size_t)b * 512 + pos;
    float s = 0.f;
#pragma unroll 4
    for (int ch = j; ch < NCH; ch += 2)
        s += pb[(size_t)ch * (BATCH * 512)];
    sm[t] = s;
    __syncthreads();
    if (t < 512) sm[t] = sm[t] + sm[t + 512];
    __syncthreads();
    if (t < NCAPS) {
        float sq = 0.f;
#pragma unroll
        for (int oo = 0; oo < NO; ++oo) {
            const float v = sm[oo * 32 + t];
            sq = fmaf(v, v, sq);
        }
        sc[t] = sq / ((1.f + sq) * sqrtf(sq));
    }
    __syncthreads();
    if (t < 512) {
        const int c = t & 31;
        const int o = t >> 5;
        const float V = sm[t] * sc[c];
        const int idx = (b * NCAPS + c) * NO + o;
        A[idx] = FIRSTCALL ? V : A[idx] + V;
        if (out) out[idx] = V;
    }
}

// ================= R12 fast path (fallback when ws can't hold U) ==================
template<int RB, bool FIRST>
__global__ __launch_bounds__(1024, 2) void caps_route_fast(
    const float* __restrict__ x, const float* __restrict__ W,
    const float* __restrict__ A, float* __restrict__ P)
{
    constexpr int NP = RB / 2;
    __shared__ __align__(16) float Ws[2][2][NCAPS * CSTR];
    __shared__ __align__(16) f2    xP[RB][8][2][NI];

    const int t  = threadIdx.x;
    const int om = (t & 3) | (((t >> 3) & 1) << 2);
    const int co = ((t >> 4) & 1) | (((t >> 2) & 1) << 1) | (((t >> 5) & 1) << 2);
    const int w  = t >> 6;
    const int oh = w & 1;
    const int bq = w >> 1;
    const int o  = oh * 8 + om;
    const int b0 = 4 * bq;
    const int r0 = blockIdx.x * RB;

    f2 a2[2][4];
    if (!FIRST) {
#pragma unroll
        for (int p = 0; p < 2; ++p)
#pragma unroll
            for (int cl = 0; cl < 4; ++cl) {
                const int c = 4 * co + cl;
                a2[p][cl].x = A[((b0 + 2 * p + 0) * NCAPS + c) * NO + o] * L2E;
                a2[p][cl].y = A[((b0 + 2 * p + 1) * NCAPS + c) * NO + o] * L2E;
            }
    }
    f2 acc[2][4];
#pragma unroll
    for (int p = 0; p < 2; ++p)
#pragma unroll
        for (int cl = 0; cl < 4; ++cl) acc[p][cl] = (f2)0.f;

    for (int s = t; s < RB * 16; s += 1024) {
        const int rr = s >> 4, bp = s & 15;
        const float* xp0 = &x[((size_t)(2 * bp + 0) * NR + r0 + rr) * NI];
        const float* xp1 = &x[((size_t)(2 * bp + 1) * NR + r0 + rr) * NI];
        const float4 a0 = *(const float4*)xp0;
        const float4 a1 = *(const float4*)(xp0 + 4);
        const float4 c0 = *(const float4*)xp1;
        const float4 c1 = *(const float4*)(xp1 + 4);
        f2* d = &xP[rr][bp >> 1][bp & 1][0];
        d[0] = f2{a0.x, c0.x}; d[1] = f2{a0.y, c0.y};
        d[2] = f2{a0.z, c0.z}; d[3] = f2{a0.w, c0.w};
        d[4] = f2{a1.x, c1.x}; d[5] = f2{a1.y, c1.y};
        d[6] = f2{a1.z, c1.z}; d[7] = f2{a1.w, c1.w};
    }

    const int c_st = t >> 5;
    const int sl   = (c_st >> 2) + 8 * (c_st & 3);
    const int part = t & 31;
    const int i_st = part >> 2;
    const int o0   = (part & 3) * 4;
    const int dst  = sl * CSTR + o0 * 12 + i_st;
    const float* wsrc = W + ((size_t)c_st * NR + r0) * (NI * NO) + part * 4;

    {
        const float4 s0 = *(const float4*)wsrc;
        const float4 s1 = *(const float4*)(wsrc + NI * NO);
        float* d0 = &Ws[0][0][dst];
        d0[0] = s0.x; d0[12] = s0.y; d0[24] = s0.z; d0[36] = s0.w;
        float* d1 = &Ws[0][1][dst];
        d1[0] = s1.x; d1[12] = s1.y; d1[24] = s1.z; d1[36] = s1.w;
    }
    float4 pfa = {}, pfb = {};
    if (NP > 1) {
        pfa = *(const float4*)(wsrc + 2 * NI * NO);
        pfb = *(const float4*)(wsrc + 3 * NI * NO);
    }
    __syncthreads();

    auto compute_r = [&](const float* wt, const f2* xv) {
        f2 xq[2][NI];
#pragma unroll
        for (int i = 0; i < NI; ++i) { xq[0][i] = xv[i]; xq[1][i] = xv[NI + i]; }
        const float* wb = wt + co * CSTR + o * 12;
        if (FIRST) {
#pragma unroll
            for (int cl = 0; cl < 4; ++cl) {
                const float* wp = wb + cl * (8 * CSTR);
                const float4 w0 = *(const float4*)wp;
                const float4 w1 = *(const float4*)(wp + 4);
#pragma unroll
                for (int p = 0; p < 2; ++p) {
                    f2 u2 = xq[p][0] * w0.x;
                    u2 += xq[p][1] * w0.y;
                    u2 += xq[p][2] * w0.z;
                    u2 += xq[p][3] * w0.w;
                    u2 += xq[p][4] * w1.x;
                    u2 += xq[p][5] * w1.y;
                    u2 += xq[p][6] * w1.z;
                    u2 += xq[p][7] * w1.w;
                    acc[p][cl] += u2;
                }
            }
        } else {
            f2 tt[2][4];
            f2 Z0 = (f2)0.f, Z1 = (f2)0.f;
#pragma unroll
            for (int cl = 0; cl < 4; ++cl) {
                const float* wp = wb + cl * (8 * CSTR);
                const float4 w0 = *(const float4*)wp;
                const float4 w1 = *(const float4*)(wp + 4);
                f2 u0 = xq[0][0] * w0.x;
                u0 += xq[0][1] * w0.y;
                u0 += xq[0][2] * w0.z;
                u0 += xq[0][3] * w0.w;
                u0 += xq[0][4] * w1.x;
                u0 += xq[0][5] * w1.y;
                u0 += xq[0][6] * w1.z;
                u0 += xq[0][7] * w1.w;
                f2 u1 = xq[1][0] * w0.x;
                u1 += xq[1][1] * w0.y;
                u1 += xq[1][2] * w0.z;
                u1 += xq[1][3] * w0.w;
                u1 += xq[1][4] * w1.x;
                u1 += xq[1][5] * w1.y;
                u1 += xq[1][6] * w1.z;
                u1 += xq[1][7] * w1.w;
                const f2 l0 = u0 * a2[0][cl];
                const f2 l1 = u1 * a2[1][cl];
                f2 e0, e1;
                e0.x = exp2f(l0.x); e0.y = exp2f(l0.y);
                e1.x = exp2f(l1.x); e1.y = exp2f(l1.y);
                Z0 += e0; Z1 += e1;
                tt[0][cl] = e0 * u0;
                tt[1][cl] = e1 * u1;
            }
#pragma unroll
            for (int m = 0; m < 3; ++m) {
                const int msk = (m == 0) ? 4 : (m == 1) ? 16 : 32;
                Z0.x += __shfl_xor(Z0.x, msk); Z0.y += __shfl_xor(Z0.y, msk);
                Z1.x += __shfl_xor(Z1.x, msk); Z1.y += __shfl_xor(Z1.y, msk);
            }
            f2 rz0, rz1;
            rz0.x = __builtin_amdgcn_rcpf(Z0.x); rz0.y = __builtin_amdgcn_rcpf(Z0.y);
            rz1.x = __builtin_amdgcn_rcpf(Z1.x); rz1.y = __builtin_amdgcn_rcpf(Z1.y);
#pragma unroll
            for (int cl = 0; cl < 4; ++cl) {
                acc[0][cl] += tt[0][cl] * rz0;
                acc[1][cl] += tt[1][cl] * rz1;
            }
        }
    };

#pragma unroll 1
    for (int rp = 0; rp < NP; ++rp) {
        const int cur = rp & 1;
        if (rp + 1 < NP) {
            float* d0 = &Ws[cur ^ 1][0][dst];
            d0[0] = pfa.x; d0[12] = pfa.y; d0[24] = pfa.z; d0[36] = pfa.w;
            float* d1 = &Ws[cur ^ 1][1][dst];
            d1[0] = pfb.x; d1[12] = pfb.y; d1[24] = pfb.z; d1[36] = pfb.w;
            if (rp + 2 < NP) {
                pfa = *(const float4*)(wsrc + (size_t)(2 * rp + 4) * (NI * NO));
                pfb = *(const float4*)(wsrc + (size_t)(2 * rp + 5) * (NI * NO));
            }
        }
        compute_r(&Ws[cur][0][0], &xP[2 * rp + 0][bq][0][0]);
        compute_r(&Ws[cur][1][0], &xP[2 * rp + 1][bq][0][0]);
        __syncthreads();
    }

#pragma unroll
    for (int bb = 0; bb < 4; ++bb) {
        const int p = bb >> 1, h = bb & 1;
        float* pout = P + (((size_t)blockIdx.x * BATCH + b0 + bb) * NO + o) * NCAPS + 4 * co;
        float4 v;
        v.x = h ? acc[p][0].y : acc[p][0].x;
        v.y = h ? acc[p][1].y : acc[p][1].x;
        v.z = h ? acc[p][2].y : acc[p][2].x;
        v.w = h ? acc[p][3].y : acc[p][3].x;
        if (FIRST) { v.x *= 0.03125f; v.y *= 0.03125f; v.z *= 0.03125f; v.w *= 0.03125f; }
        *(float4*)pout = v;
    }
}

// ---------------- generic fallback ----------------
__global__ __launch_bounds__(512, 2) void caps_route_generic(
    const float* __restrict__ x, const float* __restrict__ W,
    const float* __restrict__ A, float* __restrict__ P, int rb)
{
    __shared__ __align__(16) float Ws[NCAPS * CSTR];
    __shared__ __align__(16) float xsT[NI * MAXRB * BATCH];

    const int t = threadIdx.x;
    const int b = t & 31;
    const int o = t >> 5;
    const int r0 = blockIdx.x * rb;
    const int rbs = rb * BATCH;

    float a2s[NCAPS];
#pragma unroll
    for (int c = 0; c < NCAPS; ++c)
        a2s[c] = A[(b * NCAPS + c) * NO + o] * L2E;
    float acc[NCAPS];
#pragma unroll
    for (int c = 0; c < NCAPS; ++c) acc[c] = 0.f;

    for (int s = t; s < rbs; s += 512) {
        const int rr = s >> 5, bb = s & 31;
        const float4 v0 = *(const float4*)&x[((size_t)bb * NR + r0 + rr) * NI];
        const float4 v1 = *(const float4*)&x[((size_t)bb * NR + r0 + rr) * NI + 4];
        const float tmp[8] = {v0.x, v0.y, v0.z, v0.w, v1.x, v1.y, v1.z, v1.w};
#pragma unroll
        for (int i = 0; i < NI; ++i) xsT[i * rbs + s] = tmp[i];
    }

    const int cs  = t >> 4;
    const int seg = t & 15;
    const int iw  = seg >> 1;
    const int ob  = (seg & 1) * 8;
    const float* wsrc = W + ((size_t)cs * NR + r0) * (NI * NO) + seg * 8;
    float4 pf0 = *(const float4*)wsrc;
    float4 pf1 = *(const float4*)(wsrc + 4);

    for (int rr = 0; rr < rb; ++rr) {
        __syncthreads();
        {
            const float tmp[8] = {pf0.x, pf0.y, pf0.z, pf0.w,
                                  pf1.x, pf1.y, pf1.z, pf1.w};
#pragma unroll
            for (int k = 0; k < 8; ++k)
                Ws[cs * CSTR + (ob + k) * 12 + iw] = tmp[k];
        }
        if (rr + 1 < rb) {
            wsrc += NI * NO;
            pf0 = *(const float4*)wsrc;
            pf1 = *(const float4*)(wsrc + 4);
        }
        __syncthreads();

        float xq[NI];
#pragma unroll
        for (int i = 0; i < NI; ++i) xq[i] = xsT[i * rbs + rr * 32 + b];

        float tt[NCAPS];
        float Z = 0.f;
        const float* bp2 = &Ws[o * 12];
#pragma unroll
        for (int c = 0; c < NCAPS; ++c) {
            const float* wp = bp2 + c * CSTR;
            const float4 w0 = *(const float4*)wp;
            const float4 w1 = *(const float4*)(wp + 4);
            float uu =      xq[0] * w0.x;
            uu = fmaf(xq[1], w0.y, uu);
            uu = fmaf(xq[2], w0.z, uu);
            uu = fmaf(xq[3], w0.w, uu);
            uu = fmaf(xq[4], w1.x, uu);
            uu = fmaf(xq[5], w1.y, uu);
            uu = fmaf(xq[6], w1.z, uu);
            uu = fmaf(xq[7], w1.w, uu);
            const float ee = exp2f(uu * a2s[c]);
            Z += ee;
            tt[c] = ee * uu;
        }
        const float rz = __builtin_amdgcn_rcpf(Z);
#pragma unroll
        for (int c = 0; c < NCAPS; ++c)
            acc[c] = fmaf(tt[c], rz, acc[c]);
    }

    float* pout = P + (((size_t)blockIdx.x * BATCH + b) * NO + o) * NCAPS;
#pragma unroll
    for (int q = 0; q < NCAPS / 4; ++q) {
        float4 v;
        v.x = acc[4 * q + 0]; v.y = acc[4 * q + 1];
        v.z = acc[4 * q + 2]; v.w = acc[4 * q + 3];
        *(float4*)(pout + 4 * q) = v;
    }
}

// Fallback-path reduce (P layout [chunk][b][o][c], nchunk small).
__global__ void caps_reduce_squash(const float* __restrict__ P,
                                   float* __restrict__ A,
                                   float* __restrict__ out,
                                   int nchunk)
{
    __shared__ float sm[256];
    const int bc  = blockIdx.x;
    const int b   = bc >> 5;
    const int c   = bc & 31;
    const int tid = threadIdx.x;
    const int o = tid & 15;
    const int j = tid >> 4;
    float s = 0.f;
    for (int tch = j; tch < nchunk; tch += 16)
        s += P[(((size_t)tch * BATCH + b) * NO + o) * NCAPS + c];
    sm[tid] = s;
    __syncthreads();
    if (tid < 16) {
        float S = 0.f;
#pragma unroll
        for (int k = 0; k < 16; ++k) S += sm[tid + 16 * k];
        float sq = S * S;
#pragma unroll
        for (int d = 8; d >= 1; d >>= 1) sq += __shfl_xor(sq, d, 16);
        const float scale = sq / ((1.f + sq) * sqrtf(sq));
        const float V = S * scale;
        const int idx = bc * NO + tid;
        A[idx] += V;
        if (out) out[idx] = V;
    }
}

__global__ void caps_zero(float* __restrict__ p, int n)
{
    const int i = blockIdx.x * blockDim.x + threadIdx.x;
    if (i < n) p[i] = 0.f;
}

extern "C" void kernel_launch(void* const* d_in, const int* in_sizes, int n_in,
                              void* d_out, int out_size, void* d_ws, size_t ws_size,
                              hipStream_t stream)
{
    const float* x = (const float*)d_in[0];   // [32][4608][8]
    const float* W = (const float*)d_in[1];   // [32][4608][8][16]
    float* out = (float*)d_out;               // [32][32][16]

    const size_t elem = (size_t)BATCH * NCAPS * NO;   // 16384
    float* A  = (float*)d_ws;
    float* P  = A + elem;
    float* P2 = P + (size_t)NCH * elem;
    unsigned short* Uh = (unsigned short*)(P2 + 16 * elem);

    const size_t need_base = (size_t)(1 + NCH + 16) * elem * sizeof(float);
    const size_t need_u    = (size_t)NR * elem * sizeof(unsigned short);   // 151 MB

    if (ws_size >= need_base + need_u) {
        // Cached-U path: MFMA pass 1 computes+stores u (f16, coalesced);
        // passes 2/3 stream it at the HBM read ceiling. 7 launches total.
        caps_route_store<NR / NCH><<<NCH, 1024, 0, stream>>>(x, W, P, Uh);
        caps_squash_all<true><<<BATCH, 1024, 0, stream>>>(P, A, nullptr);
        caps_route_cached<NR / NCH><<<2 * NCH, 1024, 0, stream>>>(Uh, A, P);
        caps_squash_all<false><<<BATCH, 1024, 0, stream>>>(P, A, nullptr);
        caps_route_cached<NR / NCH><<<2 * NCH, 1024, 0, stream>>>(Uh, A, P);
        caps_squash_all<false><<<BATCH, 1024, 0, stream>>>(P, A, out);
    } else if (ws_size >= need_base) {
        // R12 fast path (proven 150.6 us structure).
        caps_route_fast<NR / NCH, true><<<NCH, 1024, 0, stream>>>(x, W, A, P);
        caps_squash_all<true><<<BATCH, 1024, 0, stream>>>(P, A, nullptr);
        caps_route_fast<NR / NCH, false><<<NCH, 1024, 0, stream>>>(x, W, A, P);
        caps_squash_all<false><<<BATCH, 1024, 0, stream>>>(P, A, nullptr);
        caps_route_fast<NR / NCH, false><<<NCH, 1024, 0, stream>>>(x, W, A, P);
        caps_squash_all<false><<<BATCH, 1024, 0, stream>>>(P, A, out);
    } else {
        caps_zero<<<(int)((elem + 255) / 256), 256, 0, stream>>>(A, (int)elem);
        int nchunk = 128;
        while (nchunk > 32 &&
               (size_t)(nchunk + 1) * elem * sizeof(float) > ws_size)
            nchunk >>= 1;
        const int rb = NR / nchunk;
        for (int it = 0; it < 3; ++it) {
            caps_route_generic<<<nchunk, 512, 0, stream>>>(x, W, A, P, rb);
            caps_reduce_squash<<<BATCH * NCAPS, 256, 0, stream>>>(
                P, A, it == 2 ? out : nullptr, nchunk);
        }
    }
}

// Round 23
// 125.811 us; speedup vs baseline: 1.2963x; 1.2963x over previous
//
#include <hip/hip_runtime.h>

#define BATCH 32
#define NCAPS 32
#define NR    4608
#define NI    8
#define NO    16
#define CSTR  200    // R12 fallback LDS stride (proven)
#define CSW   129    // MFMA W-tile stride: 129 = 1 mod 32 -> conflict-free reads
#define CSX   9      // x-tile stride: 9 coprime 32 -> conflict-free b-indexed reads
#define UTS   520    // Ut row stride (ushorts)
#define MAXRB 36
#define NCH   256
#define L2E   1.44269504088896341f

typedef float f2 __attribute__((ext_vector_type(2)));
typedef _Float16 half4v __attribute__((ext_vector_type(4)));
typedef _Float16 half8v __attribute__((ext_vector_type(8)));
typedef float f32x16 __attribute__((ext_vector_type(16)));

// ================= PASS 1 (MFMA + LDS-transposed coalesced U stores) ==============
// R21-proven: 47us, 4.43 TB/s, absmax 0.0039.
template<int RB>
__global__ __launch_bounds__(1024, 1) void caps_route_store(
    const float* __restrict__ x,    // [B][R][I]
    const float* __restrict__ W,    // [C][R][I][O]
    float* __restrict__ P,          // [NCH][B][O][C]
    unsigned short* __restrict__ Uh)// [R][B][O][C] f16
{
    constexpr int NP = RB / 2;
    __shared__ __align__(16) float Ws2[2][2][NCAPS * CSW];          // 66.0 KB
    __shared__ __align__(16) float xQ[RB][BATCH * CSX];             // 20.7 KB
    __shared__ __align__(16) unsigned short Ut[2][BATCH][UTS];      // 66.6 KB

    const int t    = threadIdx.x;
    const int lane = t & 63;
    const int wv   = t >> 6;        // wave id = o (16 waves)
    const int cc   = lane & 31;
    const int h    = lane >> 5;
    const int r0   = blockIdx.x * RB;

    for (int s = t; s < RB * BATCH; s += 1024) {
        const int rr = s >> 5, b = s & 31;
        const float* xp = &x[((size_t)b * NR + r0 + rr) * NI];
        const float4 v0 = *(const float4*)xp;
        const float4 v1 = *(const float4*)(xp + 4);
        float* d = &xQ[rr][b * CSX];
        d[0] = v0.x; d[1] = v0.y; d[2] = v0.z; d[3] = v0.w;
        d[4] = v1.x; d[5] = v1.y; d[6] = v1.z; d[7] = v1.w;
    }

    const int c_st = t >> 5;
    const int part = t & 31;
    const int dstw = c_st * CSW + part * 4;
    const float* wsrc = W + ((size_t)c_st * NR + r0) * (NI * NO) + part * 4;

    {
        const float4 s0 = *(const float4*)wsrc;
        const float4 s1 = *(const float4*)(wsrc + NI * NO);
        float* d0 = &Ws2[0][0][dstw];
        d0[0] = s0.x; d0[1] = s0.y; d0[2] = s0.z; d0[3] = s0.w;
        float* d1 = &Ws2[0][1][dstw];
        d1[0] = s1.x; d1[1] = s1.y; d1[2] = s1.z; d1[3] = s1.w;
    }
    float4 pfa = {}, pfb = {};
    if (NP > 1) {
        pfa = *(const float4*)(wsrc + 2 * NI * NO);
        pfb = *(const float4*)(wsrc + 3 * NI * NO);
    }
    __syncthreads();

    f32x16 acc = (f32x16)0.f;
    const int xoff = cc * CSX + 4 * h;
    const int woff = cc * CSW + 64 * h + wv;
    const size_t S = (size_t)BATCH * NO * NCAPS;   // ushorts per r-slab

#pragma unroll 1
    for (int rp = 0; rp < NP; ++rp) {
        const int cur = rp & 1;
        if (rp + 1 < NP) {
            float* d0 = &Ws2[cur ^ 1][0][dstw];
            d0[0] = pfa.x; d0[1] = pfa.y; d0[2] = pfa.z; d0[3] = pfa.w;
            float* d1 = &Ws2[cur ^ 1][1][dstw];
            d1[0] = pfb.x; d1[1] = pfb.y; d1[2] = pfb.z; d1[3] = pfb.w;
            if (rp + 2 < NP) {
                pfa = *(const float4*)(wsrc + (size_t)(2 * rp + 4) * (NI * NO));
                pfb = *(const float4*)(wsrc + (size_t)(2 * rp + 5) * (NI * NO));
            }
        }

#pragma unroll
        for (int sub = 0; sub < 2; ++sub) {
            const float* xr = &xQ[2 * rp + sub][xoff];
            const float* wr = &Ws2[cur][sub][woff];
            half4v af, bf;
            af[0] = (_Float16)xr[0]; af[1] = (_Float16)xr[1];
            af[2] = (_Float16)xr[2]; af[3] = (_Float16)xr[3];
            bf[0] = (_Float16)wr[0];  bf[1] = (_Float16)wr[16];
            bf[2] = (_Float16)wr[32]; bf[3] = (_Float16)wr[48];
            const f32x16 u =
                __builtin_amdgcn_mfma_f32_32x32x8f16(af, bf, (f32x16)0.f, 0, 0, 0);
            acc += u;
#pragma unroll
            for (int k = 0; k < 16; ++k) {
                const int b = (k & 3) + 8 * (k >> 2) + 4 * h;
                const _Float16 hv = (_Float16)u[k];
                Ut[sub][b][wv * NCAPS + cc] = __builtin_bit_cast(unsigned short, hv);
            }
        }
        __syncthreads();   // Ut complete (and next Ws2 staged)

#pragma unroll
        for (int sub = 0; sub < 2; ++sub) {
            const size_t rbase = (size_t)(r0 + 2 * rp + sub) * S;
#pragma unroll
            for (int q = 0; q < 2; ++q) {
                const int s = t + 1024 * q;
                const int b = s >> 6;
                const int j = s & 63;
                const uint4 v = *(const uint4*)&Ut[sub][b][j * 8];
                *(uint4*)(Uh + rbase + (size_t)s * 8) = v;
            }
        }
        __syncthreads();   // Ut reads done before next writes
    }

    float* pb = P + ((size_t)blockIdx.x * BATCH * NO + wv) * NCAPS + cc;
#pragma unroll
    for (int k = 0; k < 16; ++k) {
        const int b = (k & 3) + 8 * (k >> 2) + 4 * h;
        pb[(size_t)b * (NO * NCAPS)] = acc[k] * 0.03125f;
    }
}

// ================= PASS 2/3: streaming softmax from cached U (at read ceiling) ====
template<int RB>
__global__ __launch_bounds__(1024, 2) void caps_route_cached(
    const unsigned short* __restrict__ Uh,  // [R][B][O][C] f16
    const float* __restrict__ A,            // [B][C][O]
    float* __restrict__ P)                  // [NCH][B][O][C]
{
    const int t     = threadIdx.x;
    const int ch2   = t & 3;
    const int o     = (t >> 2) & 15;
    const int brel  = t >> 6;
    const int chunk = blockIdx.x >> 1;
    const int b     = 16 * (blockIdx.x & 1) + brel;
    const int r0    = chunk * RB;

    float a2[8];
#pragma unroll
    for (int cc = 0; cc < 8; ++cc)
        a2[cc] = A[(b * NCAPS + 8 * ch2 + cc) * NO + o] * L2E;
    float acc[8];
#pragma unroll
    for (int cc = 0; cc < 8; ++cc) acc[cc] = 0.f;

    const size_t S = (size_t)BATCH * NO * NCAPS;
    const unsigned short* up =
        Uh + (((size_t)r0 * BATCH + b) * NO + o) * NCAPS + 8 * ch2;

    uint4 q = *(const uint4*)up;
#pragma unroll 1
    for (int rr = 0; rr < RB; ++rr) {
        uint4 n = {};
        if (rr + 1 < RB) n = *(const uint4*)(up + S);
        up += S;

        const half8v h = __builtin_bit_cast(half8v, q);
        float Z = 0.f;
        float tt[8];
#pragma unroll
        for (int cc = 0; cc < 8; ++cc) {
            const float uu = (float)h[cc];
            const float ee = exp2f(uu * a2[cc]);
            Z += ee;
            tt[cc] = ee * uu;
        }
        Z += __shfl_xor(Z, 1);
        Z += __shfl_xor(Z, 2);
        const float rz = __builtin_amdgcn_rcpf(Z);
#pragma unroll
        for (int cc = 0; cc < 8; ++cc)
            acc[cc] = fmaf(tt[cc], rz, acc[cc]);

        q = n;
    }

    float* pout = P + (((size_t)chunk * BATCH + b) * NO + o) * NCAPS + 8 * ch2;
    float4 v0, v1;
    v0.x = acc[0]; v0.y = acc[1]; v0.z = acc[2]; v0.w = acc[3];
    v1.x = acc[4]; v1.y = acc[5]; v1.z = acc[6]; v1.w = acc[7];
    *(float4*)pout = v0;
    *(float4*)(pout + 4) = v1;
}

// Stage-1 reduce: coalesced float4 column sums of P[256][16384] -> P2[16][16384].
__global__ __launch_bounds__(256) void caps_partial(const float* __restrict__ P,
                                                    float* __restrict__ P2)
{
    const int tid = threadIdx.x;
    const int ct  = blockIdx.x & 15;
    const int rg  = blockIdx.x >> 4;
    const size_t col = (size_t)ct * 1024 + tid * 4;
    const float* p = P + (size_t)rg * 16 * 16384 + col;
    float4 s = {0.f, 0.f, 0.f, 0.f};
#pragma unroll
    for (int k = 0; k < 16; ++k) {
        const float4 v = *(const float4*)(p + (size_t)k * 16384);
        s.x += v.x; s.y += v.y; s.z += v.z; s.w += v.w;
    }
    *(float4*)(P2 + (size_t)rg * 16384 + col) = s;
}

// Stage-2: per-b coalesced reduce of P2 + squash + A update (32 x 512).
// FIRSTCALL: A = V (folds in the zeroing; A is never read before this).
template<bool FIRSTCALL>
__global__ __launch_bounds__(512) void caps_squash32(
    const float* __restrict__ P2,
    float* __restrict__ A,
    float* __restrict__ out)
{
    __shared__ float sm[512];
    __shared__ float sc[NCAPS];
    const int b = blockIdx.x;
    const int t = threadIdx.x;      // = o*32 + c
    const int c = t & 31;
    const int o = t >> 5;
    float s = 0.f;
#pragma unroll
    for (int g = 0; g < 16; ++g)
        s += P2[(size_t)g * 16384 + b * 512 + t];
    sm[t] = s;
    __syncthreads();
    if (t < NCAPS) {
        float sq = 0.f;
#pragma unroll
        for (int oo = 0; oo < NO; ++oo) {
            const float v = sm[oo * 32 + t];
            sq = fmaf(v, v, sq);
        }
        sc[t] = sq / ((1.f + sq) * sqrtf(sq));
    }
    __syncthreads();
    const float V = s * sc[c];
    const int idx = (b * NCAPS + c) * NO + o;
    A[idx] = FIRSTCALL ? V : A[idx] + V;
    if (out) out[idx] = V;
}

// ================= R12 fast path (fallback when ws can't hold U) ==================
template<int RB, bool FIRST>
__global__ __launch_bounds__(1024, 2) void caps_route_fast(
    const float* __restrict__ x, const float* __restrict__ W,
    const float* __restrict__ A, float* __restrict__ P)
{
    constexpr int NP = RB / 2;
    __shared__ __align__(16) float Ws[2][2][NCAPS * CSTR];
    __shared__ __align__(16) f2    xP[RB][8][2][NI];

    const int t  = threadIdx.x;
    const int om = (t & 3) | (((t >> 3) & 1) << 2);
    const int co = ((t >> 4) & 1) | (((t >> 2) & 1) << 1) | (((t >> 5) & 1) << 2);
    const int w  = t >> 6;
    const int oh = w & 1;
    const int bq = w >> 1;
    const int o  = oh * 8 + om;
    const int b0 = 4 * bq;
    const int r0 = blockIdx.x * RB;

    f2 a2[2][4];
    if (!FIRST) {
#pragma unroll
        for (int p = 0; p < 2; ++p)
#pragma unroll
            for (int cl = 0; cl < 4; ++cl) {
                const int c = 4 * co + cl;
                a2[p][cl].x = A[((b0 + 2 * p + 0) * NCAPS + c) * NO + o] * L2E;
                a2[p][cl].y = A[((b0 + 2 * p + 1) * NCAPS + c) * NO + o] * L2E;
            }
    }
    f2 acc[2][4];
#pragma unroll
    for (int p = 0; p < 2; ++p)
#pragma unroll
        for (int cl = 0; cl < 4; ++cl) acc[p][cl] = (f2)0.f;

    for (int s = t; s < RB * 16; s += 1024) {
        const int rr = s >> 4, bp = s & 15;
        const float* xp0 = &x[((size_t)(2 * bp + 0) * NR + r0 + rr) * NI];
        const float* xp1 = &x[((size_t)(2 * bp + 1) * NR + r0 + rr) * NI];
        const float4 a0 = *(const float4*)xp0;
        const float4 a1 = *(const float4*)(xp0 + 4);
        const float4 c0 = *(const float4*)xp1;
        const float4 c1 = *(const float4*)(xp1 + 4);
        f2* d = &xP[rr][bp >> 1][bp & 1][0];
        d[0] = f2{a0.x, c0.x}; d[1] = f2{a0.y, c0.y};
        d[2] = f2{a0.z, c0.z}; d[3] = f2{a0.w, c0.w};
        d[4] = f2{a1.x, c1.x}; d[5] = f2{a1.y, c1.y};
        d[6] = f2{a1.z, c1.z}; d[7] = f2{a1.w, c1.w};
    }

    const int c_st = t >> 5;
    const int sl   = (c_st >> 2) + 8 * (c_st & 3);
    const int part = t & 31;
    const int i_st = part >> 2;
    const int o0   = (part & 3) * 4;
    const int dst  = sl * CSTR + o0 * 12 + i_st;
    const float* wsrc = W + ((size_t)c_st * NR + r0) * (NI * NO) + part * 4;

    {
        const float4 s0 = *(const float4*)wsrc;
        const float4 s1 = *(const float4*)(wsrc + NI * NO);
        float* d0 = &Ws[0][0][dst];
        d0[0] = s0.x; d0[12] = s0.y; d0[24] = s0.z; d0[36] = s0.w;
        float* d1 = &Ws[0][1][dst];
        d1[0] = s1.x; d1[12] = s1.y; d1[24] = s1.z; d1[36] = s1.w;
    }
    float4 pfa = {}, pfb = {};
    if (NP > 1) {
        pfa = *(const float4*)(wsrc + 2 * NI * NO);
        pfb = *(const float4*)(wsrc + 3 * NI * NO);
    }
    __syncthreads();

    auto compute_r = [&](const float* wt, const f2* xv) {
        f2 xq[2][NI];
#pragma unroll
        for (int i = 0; i < NI; ++i) { xq[0][i] = xv[i]; xq[1][i] = xv[NI + i]; }
        const float* wb = wt + co * CSTR + o * 12;
        if (FIRST) {
#pragma unroll
            for (int cl = 0; cl < 4; ++cl) {
                const float* wp = wb + cl * (8 * CSTR);
                const float4 w0 = *(const float4*)wp;
                const float4 w1 = *(const float4*)(wp + 4);
#pragma unroll
                for (int p = 0; p < 2; ++p) {
                    f2 u2 = xq[p][0] * w0.x;
                    u2 += xq[p][1] * w0.y;
                    u2 += xq[p][2] * w0.z;
                    u2 += xq[p][3] * w0.w;
                    u2 += xq[p][4] * w1.x;
                    u2 += xq[p][5] * w1.y;
                    u2 += xq[p][6] * w1.z;
                    u2 += xq[p][7] * w1.w;
                    acc[p][cl] += u2;
                }
            }
        } else {
            f2 tt[2][4];
            f2 Z0 = (f2)0.f, Z1 = (f2)0.f;
#pragma unroll
            for (int cl = 0; cl < 4; ++cl) {
                const float* wp = wb + cl * (8 * CSTR);
                const float4 w0 = *(const float4*)wp;
                const float4 w1 = *(const float4*)(wp + 4);
                f2 u0 = xq[0][0] * w0.x;
                u0 += xq[0][1] * w0.y;
                u0 += xq[0][2] * w0.z;
                u0 += xq[0][3] * w0.w;
                u0 += xq[0][4] * w1.x;
                u0 += xq[0][5] * w1.y;
                u0 += xq[0][6] * w1.z;
                u0 += xq[0][7] * w1.w;
                f2 u1 = xq[1][0] * w0.x;
                u1 += xq[1][1] * w0.y;
                u1 += xq[1][2] * w0.z;
                u1 += xq[1][3] * w0.w;
                u1 += xq[1][4] * w1.x;
                u1 += xq[1][5] * w1.y;
                u1 += xq[1][6] * w1.z;
                u1 += xq[1][7] * w1.w;
                const f2 l0 = u0 * a2[0][cl];
                const f2 l1 = u1 * a2[1][cl];
                f2 e0, e1;
                e0.x = exp2f(l0.x); e0.y = exp2f(l0.y);
                e1.x = exp2f(l1.x); e1.y = exp2f(l1.y);
                Z0 += e0; Z1 += e1;
                tt[0][cl] = e0 * u0;
                tt[1][cl] = e1 * u1;
            }
#pragma unroll
            for (int m = 0; m < 3; ++m) {
                const int msk = (m == 0) ? 4 : (m == 1) ? 16 : 32;
                Z0.x += __shfl_xor(Z0.x, msk); Z0.y += __shfl_xor(Z0.y, msk);
                Z1.x += __shfl_xor(Z1.x, msk); Z1.y += __shfl_xor(Z1.y, msk);
            }
            f2 rz0, rz1;
            rz0.x = __builtin_amdgcn_rcpf(Z0.x); rz0.y = __builtin_amdgcn_rcpf(Z0.y);
            rz1.x = __builtin_amdgcn_rcpf(Z1.x); rz1.y = __builtin_amdgcn_rcpf(Z1.y);
#pragma unroll
            for (int cl = 0; cl < 4; ++cl) {
                acc[0][cl] += tt[0][cl] * rz0;
                acc[1][cl] += tt[1][cl] * rz1;
            }
        }
    };

#pragma unroll 1
    for (int rp = 0; rp < NP; ++rp) {
        const int cur = rp & 1;
        if (rp + 1 < NP) {
            float* d0 = &Ws[cur ^ 1][0][dst];
            d0[0] = pfa.x; d0[12] = pfa.y; d0[24] = pfa.z; d0[36] = pfa.w;
            float* d1 = &Ws[cur ^ 1][1][dst];
            d1[0] = pfb.x; d1[12] = pfb.y; d1[24] = pfb.z; d1[36] = pfb.w;
            if (rp + 2 < NP) {
                pfa = *(const float4*)(wsrc + (size_t)(2 * rp + 4) * (NI * NO));
                pfb = *(const float4*)(wsrc + (size_t)(2 * rp + 5) * (NI * NO));
            }
        }
        compute_r(&Ws[cur][0][0], &xP[2 * rp + 0][bq][0][0]);
        compute_r(&Ws[cur][1][0], &xP[2 * rp + 1][bq][0][0]);
        __syncthreads();
    }

#pragma unroll
    for (int bb = 0; bb < 4; ++bb) {
        const int p = bb >> 1, h = bb & 1;
        float* pout = P + (((size_t)blockIdx.x * BATCH + b0 + bb) * NO + o) * NCAPS + 4 * co;
        float4 v;
        v.x = h ? acc[p][0].y : acc[p][0].x;
        v.y = h ? acc[p][1].y : acc[p][1].x;
        v.z = h ? acc[p][2].y : acc[p][2].x;
        v.w = h ? acc[p][3].y : acc[p][3].x;
        if (FIRST) { v.x *= 0.03125f; v.y *= 0.03125f; v.z *= 0.03125f; v.w *= 0.03125f; }
        *(float4*)pout = v;
    }
}

// ---------------- generic fallback ----------------
__global__ __launch_bounds__(512, 2) void caps_route_generic(
    const float* __restrict__ x, const float* __restrict__ W,
    const float* __restrict__ A, float* __restrict__ P, int rb)
{
    __shared__ __align__(16) float Ws[NCAPS * CSTR];
    __shared__ __align__(16) float xsT[NI * MAXRB * BATCH];

    const int t = threadIdx.x;
    const int b = t & 31;
    const int o = t >> 5;
    const int r0 = blockIdx.x * rb;
    const int rbs = rb * BATCH;

    float a2s[NCAPS];
#pragma unroll
    for (int c = 0; c < NCAPS; ++c)
        a2s[c] = A[(b * NCAPS + c) * NO + o] * L2E;
    float acc[NCAPS];
#pragma unroll
    for (int c = 0; c < NCAPS; ++c) acc[c] = 0.f;

    for (int s = t; s < rbs; s += 512) {
        const int rr = s >> 5, bb = s & 31;
        const float4 v0 = *(const float4*)&x[((size_t)bb * NR + r0 + rr) * NI];
        const float4 v1 = *(const float4*)&x[((size_t)bb * NR + r0 + rr) * NI + 4];
        const float tmp[8] = {v0.x, v0.y, v0.z, v0.w, v1.x, v1.y, v1.z, v1.w};
#pragma unroll
        for (int i = 0; i < NI; ++i) xsT[i * rbs + s] = tmp[i];
    }

    const int cs  = t >> 4;
    const int seg = t & 15;
    const int iw  = seg >> 1;
    const int ob  = (seg & 1) * 8;
    const float* wsrc = W + ((size_t)cs * NR + r0) * (NI * NO) + seg * 8;
    float4 pf0 = *(const float4*)wsrc;
    float4 pf1 = *(const float4*)(wsrc + 4);

    for (int rr = 0; rr < rb; ++rr) {
        __syncthreads();
        {
            const float tmp[8] = {pf0.x, pf0.y, pf0.z, pf0.w,
                                  pf1.x, pf1.y, pf1.z, pf1.w};
#pragma unroll
            for (int k = 0; k < 8; ++k)
                Ws[cs * CSTR + (ob + k) * 12 + iw] = tmp[k];
        }
        if (rr + 1 < rb) {
            wsrc += NI * NO;
            pf0 = *(const float4*)wsrc;
            pf1 = *(const float4*)(wsrc + 4);
        }
        __syncthreads();

        float xq[NI];
#pragma unroll
        for (int i = 0; i < NI; ++i) xq[i] = xsT[i * rbs + rr * 32 + b];

        float tt[NCAPS];
        float Z = 0.f;
        const float* bp2 = &Ws[o * 12];
#pragma unroll
        for (int c = 0; c < NCAPS; ++c) {
            const float* wp = bp2 + c * CSTR;
            const float4 w0 = *(const float4*)wp;
            const float4 w1 = *(const float4*)(wp + 4);
            float uu =      xq[0] * w0.x;
            uu = fmaf(xq[1], w0.y, uu);
            uu = fmaf(xq[2], w0.z, uu);
            uu = fmaf(xq[3], w0.w, uu);
            uu = fmaf(xq[4], w1.x, uu);
            uu = fmaf(xq[5], w1.y, uu);
            uu = fmaf(xq[6], w1.z, uu);
            uu = fmaf(xq[7], w1.w, uu);
            const float ee = exp2f(uu * a2s[c]);
            Z += ee;
            tt[c] = ee * uu;
        }
        const float rz = __builtin_amdgcn_rcpf(Z);
#pragma unroll
        for (int c = 0; c < NCAPS; ++c)
            acc[c] = fmaf(tt[c], rz, acc[c]);
    }

    float* pout = P + (((size_t)blockIdx.x * BATCH + b) * NO + o) * NCAPS;
#pragma unroll
    for (int q = 0; q < NCAPS / 4; ++q) {
        float4 v;
        v.x = acc[4 * q + 0]; v.y = acc[4 * q + 1];
        v.z = acc[4 * q + 2]; v.w = acc[4 * q + 3];
        *(float4*)(pout + 4 * q) = v;
    }
}

// Fallback-path reduce (P layout [chunk][b][o][c], nchunk small).
__global__ void caps_reduce_squash(const float* __restrict__ P,
                                   float* __restrict__ A,
                                   float* __restrict__ out,
                                   int nchunk)
{
    __shared__ float sm[256];
    const int bc  = blockIdx.x;
    const int b   = bc >> 5;
    const int c   = bc & 31;
    const int tid = threadIdx.x;
    const int o = tid & 15;
    const int j = tid >> 4;
    float s = 0.f;
    for (int tch = j; tch < nchunk; tch += 16)
        s += P[(((size_t)tch * BATCH + b) * NO + o) * NCAPS + c];
    sm[tid] = s;
    __syncthreads();
    if (tid < 16) {
        float S = 0.f;
#pragma unroll
        for (int k = 0; k < 16; ++k) S += sm[tid + 16 * k];
        float sq = S * S;
#pragma unroll
        for (int d = 8; d >= 1; d >>= 1) sq += __shfl_xor(sq, d, 16);
        const float scale = sq / ((1.f + sq) * sqrtf(sq));
        const float V = S * scale;
        const int idx = bc * NO + tid;
        A[idx] += V;
        if (out) out[idx] = V;
    }
}

__global__ void caps_zero(float* __restrict__ p, int n)
{
    const int i = blockIdx.x * blockDim.x + threadIdx.x;
    if (i < n) p[i] = 0.f;
}

extern "C" void kernel_launch(void* const* d_in, const int* in_sizes, int n_in,
                              void* d_out, int out_size, void* d_ws, size_t ws_size,
                              hipStream_t stream)
{
    const float* x = (const float*)d_in[0];   // [32][4608][8]
    const float* W = (const float*)d_in[1];   // [32][4608][8][16]
    float* out = (float*)d_out;               // [32][32][16]

    const size_t elem = (size_t)BATCH * NCAPS * NO;   // 16384
    float* A  = (float*)d_ws;
    float* P  = A + elem;
    float* P2 = P + (size_t)NCH * elem;
    unsigned short* Uh = (unsigned short*)(P2 + 16 * elem);

    const size_t need_base = (size_t)(1 + NCH + 16) * elem * sizeof(float);
    const size_t need_u    = (size_t)NR * elem * sizeof(unsigned short);   // 151 MB

    if (ws_size >= need_base + need_u) {
        // Cached-U path (R21 structure, 9 launches): MFMA pass 1 computes+stores
        // u (f16, coalesced); passes 2/3 stream it at the HBM read ceiling.
        caps_route_store<NR / NCH><<<NCH, 1024, 0, stream>>>(x, W, P, Uh);
        caps_partial<<<256, 256, 0, stream>>>(P, P2);
        caps_squash32<true><<<BATCH, 512, 0, stream>>>(P2, A, nullptr);
        caps_route_cached<NR / NCH><<<2 * NCH, 1024, 0, stream>>>(Uh, A, P);
        caps_partial<<<256, 256, 0, stream>>>(P, P2);
        caps_squash32<false><<<BATCH, 512, 0, stream>>>(P2, A, nullptr);
        caps_route_cached<NR / NCH><<<2 * NCH, 1024, 0, stream>>>(Uh, A, P);
        caps_partial<<<256, 256, 0, stream>>>(P, P2);
        caps_squash32<false><<<BATCH, 512, 0, stream>>>(P2, A, out);
    } else if (ws_size >= need_base) {
        // R12 fast path (proven 150.6 us structure).
        caps_route_fast<NR / NCH, true><<<NCH, 1024, 0, stream>>>(x, W, A, P);
        caps_partial<<<256, 256, 0, stream>>>(P, P2);
        caps_squash32<true><<<BATCH, 512, 0, stream>>>(P2, A, nullptr);
        caps_route_fast<NR / NCH, false><<<NCH, 1024, 0, stream>>>(x, W, A, P);
        caps_partial<<<256, 256, 0, stream>>>(P, P2);
        caps_squash32<false><<<BATCH, 512, 0, stream>>>(P2, A, nullptr);
        caps_route_fast<NR / NCH, false><<<NCH, 1024, 0, stream>>>(x, W, A, P);
        caps_partial<<<256, 256, 0, stream>>>(P, P2);
        caps_squash32<false><<<BATCH, 512, 0, stream>>>(P2, A, out);
    } else {
        caps_zero<<<(int)((elem + 255) / 256), 256, 0, stream>>>(A, (int)elem);
        int nchunk = 128;
        while (nchunk > 32 &&
               (size_t)(nchunk + 1) * elem * sizeof(float) > ws_size)
            nchunk >>= 1;
        const int rb = NR / nchunk;
        for (int it = 0; it < 3; ++it) {
            caps_route_generic<<<nchunk, 512, 0, stream>>>(x, W, A, P, rb);
            caps_reduce_squash<<<BATCH * NCAPS, 256, 0, stream>>>(
                P, A, it == 2 ? out : nullptr, nchunk);
        }
    }
}